// Round 16
// baseline (133.686 us; speedup 1.0000x reference)
//
#include <hip/hip_runtime.h>

typedef __attribute__((ext_vector_type(8))) __bf16 bf16x8;
typedef __attribute__((ext_vector_type(4))) float f32x4;
typedef __attribute__((ext_vector_type(16))) float f32x16;
typedef __attribute__((ext_vector_type(8))) unsigned short u16x8;

#define MFMA16(a, b, c) __builtin_amdgcn_mfma_f32_16x16x32_bf16((a), (b), (c), 0, 0, 0)
#define MFMA32(a, b, c) __builtin_amdgcn_mfma_f32_32x32x16_bf16((a), (b), (c), 0, 0, 0)

// async global->LDS, 16B per lane; dst must be wave-uniform base (lane*16B auto)
#define GLDS16(g, l) __builtin_amdgcn_global_load_lds( \
    (const __attribute__((address_space(1))) unsigned int*)(const void*)(g), \
    (__attribute__((address_space(3))) unsigned int*)(void*)(l), 16, 0, 0)

__device__ __forceinline__ unsigned short bfc(float f) {
    __bf16 h = (__bf16)f;
    return __builtin_bit_cast(unsigned short, h);
}
__device__ __forceinline__ float bf2f(unsigned short u) {
    return __builtin_bit_cast(float, (unsigned int)u << 16);
}

// ---------------------------------------------------------------- prep2: converts + WkE/WvF fold, one launch
// blocks [0,1536): f32->bf16 of x,Wq,Wp (4 float4/thread ILP).  [1536,2048): build WkE/WvF.
__global__ __launch_bounds__(256) void prep2(
    const float* __restrict__ x, const float* __restrict__ wq, const float* __restrict__ wp,
    const float* __restrict__ Wk, const float* __restrict__ Wv,
    const float* __restrict__ E, const float* __restrict__ F,
    unsigned short* __restrict__ xb, unsigned short* __restrict__ wcat, unsigned short* __restrict__ wpb) {
    __shared__ float Els[4096];          // build part only (16 KB)
    const int tid = threadIdx.x;
    if (blockIdx.x < 1536) {
        int i0 = (blockIdx.x * 256 + tid) * 4;    // float4 index, [0, 1572864)
        const float* s; unsigned short* d;
        if (i0 < 1048576)      { s = x;  d = xb; }
        else if (i0 < 1310720) { i0 -= 1048576; s = wq; d = wcat; }
        else                   { i0 -= 1310720; s = wp; d = wpb; }
#pragma unroll
        for (int k = 0; k < 4; ++k) {
            float4 v = reinterpret_cast<const float4*>(s)[i0 + k];
            ushort4 o;
            o.x = bfc(v.x); o.y = bfc(v.y); o.z = bfc(v.z); o.w = bfc(v.w);
            reinterpret_cast<ushort4*>(d)[i0 + k] = o;
        }
        return;
    }
    const int bx = blockIdx.x - 1536;    // [0,512): sel(2) x h(16) x cs(16)
    const int sel = bx >> 8, h = (bx >> 4) & 15, cs = bx & 15;
    const int ko = tid >> 4, cq = tid & 15;
    const int c = cs * 64 + cq * 4;

    const float* W  = sel ? Wv : Wk;
    const float* Ef = (sel ? F : E) + (size_t)h * 4096;
#pragma unroll
    for (int i = tid; i < 1024; i += 256)
        reinterpret_cast<float4*>(Els)[i] = reinterpret_cast<const float4*>(Ef)[i];
    __syncthreads();

    float acc[4][4];
#pragma unroll
    for (int j = 0; j < 4; ++j)
#pragma unroll
        for (int t = 0; t < 4; ++t) acc[j][t] = 0.f;

#pragma unroll 8
    for (int d = 0; d < 64; ++d) {
        float4 wv4 = *reinterpret_cast<const float4*>(&W[(size_t)(h * 64 + d) * 1024 + c]);
        float4 e = *reinterpret_cast<const float4*>(&Els[d * 64 + ko * 4]);
        float ev[4] = {e.x, e.y, e.z, e.w};
#pragma unroll
        for (int j = 0; j < 4; ++j) {
            acc[j][0] = fmaf(ev[j], wv4.x, acc[j][0]);
            acc[j][1] = fmaf(ev[j], wv4.y, acc[j][1]);
            acc[j][2] = fmaf(ev[j], wv4.z, acc[j][2]);
            acc[j][3] = fmaf(ev[j], wv4.w, acc[j][3]);
        }
    }
#pragma unroll
    for (int j = 0; j < 4; ++j) {
        const int row = 1024 + (sel << 10) + h * 64 + ko * 4 + j;
        ushort4 o;
        o.x = bfc(acc[j][0]); o.y = bfc(acc[j][1]); o.z = bfc(acc[j][2]); o.w = bfc(acc[j][3]);
        *reinterpret_cast<ushort4*>(&wcat[(size_t)row * 1024 + c]) = o;
    }
}

// ---------------------------------------------------------------- bf16 GEMM, B^T layout
// 2-phase double-buffered staging: 1 barrier/iter, loads fly under compute.
template <int MODE>
__global__ __launch_bounds__(256) void gemm_bt(
    const unsigned short* __restrict__ A, const unsigned short* __restrict__ Bt, int K,
    unsigned short* __restrict__ qo, unsigned short* __restrict__ kpo, unsigned short* __restrict__ vpto,
    float* __restrict__ out, const float* __restrict__ bp) {
    __shared__ __align__(16) unsigned short As[2][4096];
    __shared__ __align__(16) unsigned short Bs[2][4096];
    const int tid = threadIdx.x;
    const int lane = tid & 63, wv = tid >> 6;
    const int g = lane >> 4, ln = lane & 15;
    const int wm = wv >> 1, wn = wv & 1;
    const int m0 = blockIdx.x * 128, n0 = blockIdx.y * 128;
    const int wvb = wv * 512;

    f32x4 acc[4][4];
#pragma unroll
    for (int i = 0; i < 4; ++i)
#pragma unroll
        for (int j = 0; j < 4; ++j) acc[i][j] = (f32x4){0.f, 0.f, 0.f, 0.f};

    const int c0 = tid, c1 = 256 + tid;
    const int row0 = c0 >> 2, k80 = c0 & 3;
    const int row1 = c1 >> 2, k81 = c1 & 3;

    auto stage = [&](int buf, int kt) {
        const int kb = kt * 32;
        GLDS16(A  + (size_t)(m0 + row0) * K + kb + k80 * 8, As[buf] + wvb);
        GLDS16(A  + (size_t)(m0 + row1) * K + kb + k81 * 8, As[buf] + 2048 + wvb);
        GLDS16(Bt + (size_t)(n0 + row0) * K + kb + k80 * 8, Bs[buf] + wvb);
        GLDS16(Bt + (size_t)(n0 + row1) * K + kb + k81 * 8, Bs[buf] + 2048 + wvb);
    };

    const int nk = K >> 5;
    stage(0, 0);
    for (int kt = 0; kt < nk; ++kt) {
        const int cur = kt & 1;
        __syncthreads();                          // buf[cur] landed; buf[cur^1] reads done
        if (kt + 1 < nk) stage(cur ^ 1, kt + 1);  // next-tile loads fly under this compute
        bf16x8 af[4], bfr[4];
#pragma unroll
        for (int i = 0; i < 4; ++i)
            af[i] = __builtin_bit_cast(bf16x8, *reinterpret_cast<const u16x8*>(As[cur] + (wm * 64 + i * 16 + ln) * 32 + g * 8));
#pragma unroll
        for (int j = 0; j < 4; ++j)
            bfr[j] = __builtin_bit_cast(bf16x8, *reinterpret_cast<const u16x8*>(Bs[cur] + (wn * 64 + j * 16 + ln) * 32 + g * 8));
#pragma unroll
        for (int i = 0; i < 4; ++i)
#pragma unroll
            for (int j = 0; j < 4; ++j)
                acc[i][j] = MFMA16(af[i], bfr[j], acc[i][j]);
    }

#pragma unroll
    for (int i = 0; i < 4; ++i) {
        const int mbase = m0 + wm * 64 + i * 16 + 4 * g;
        const int b = mbase >> 11, t0 = mbase & 2047;
#pragma unroll
        for (int j = 0; j < 4; ++j) {
            const int ncol = n0 + wn * 64 + j * 16 + ln;
            if (MODE == 0) {
                const int sec = ncol >> 10, nn = ncol & 1023;
                const int h = nn >> 6, e = nn & 63;
                const int bh = b * 16 + h;
                if (sec == 2) {
                    ushort4 o;
                    o.x = bfc(acc[i][j][0]); o.y = bfc(acc[i][j][1]);
                    o.z = bfc(acc[i][j][2]); o.w = bfc(acc[i][j][3]);
                    *reinterpret_cast<ushort4*>(&vpto[(size_t)(bh * 64 + e) * 2048 + t0]) = o;
                } else {
#pragma unroll
                    for (int r = 0; r < 4; ++r) {
                        unsigned short val = bfc(acc[i][j][r]);
                        if (sec == 0) qo[(size_t)(bh * 2048 + t0 + r) * 64 + e] = val;
                        else          kpo[(size_t)(bh * 2048 + t0 + r) * 64 + e] = val;
                    }
                }
            } else {
#pragma unroll
                for (int r = 0; r < 4; ++r)
                    out[(size_t)(mbase + r) * 1024 + ncol] = acc[i][j][r] + bp[ncol];
            }
        }
    }
}

// ---------------------------------------------------------------- split-K flash attention, phase A
// Fixed-offset softmax: P = exp2(S*CS), l via ones-MFMA. 3-buffer KV ring +
// counted vmcnt. nc==1 WUs (p<4) normalize in-kernel and write og directly
// (skip pO/pML roundtrip); multi-chunk WUs go through separate merge dispatch
// (R13: fused merge w/ threadfence+atomic across XCDs cost 7x).
__attribute__((amdgpu_waves_per_eu(3, 4)))
__global__ __launch_bounds__(256) void attn_part(
    const unsigned short* __restrict__ qg, const unsigned short* __restrict__ kpg,
    const unsigned short* __restrict__ vptg,
    unsigned short* __restrict__ pO, float* __restrict__ pML,
    unsigned short* __restrict__ og) {
    const int bx = blockIdx.x;                    // [0,1280)
    const int xcd = bx & 7;
    const int j = bx >> 3;                        // [0,160)
    const int bhl = j & 3;
    const int u = 39 - (j >> 2);                  // long chunks first
    const int bh = xcd * 4 + bhl;                 // 4 heads per XCD
    int p, c;
    if (u < 4)       { p = u;                    c = 0; }
    else if (u < 12) { p = 4 + ((u - 4) >> 1);   c = (u - 4) & 1; }
    else if (u < 24) { p = 8 + (u - 12) / 3;     c = (u - 12) % 3; }
    else             { p = 12 + ((u - 24) >> 2); c = (u - 24) & 3; }
    int ubase;
    if (p < 4)       ubase = p;
    else if (p < 8)  ubase = 4 + 2 * (p - 4);
    else if (p < 12) ubase = 12 + 3 * (p - 8);
    else             ubase = 24 + 4 * (p - 12);
    const int tiles = (p == 15) ? 32 : (2 * p + 2);
    const int stBeg = c * 8;
    const int stEnd = (stBeg + 8 < tiles) ? stBeg + 8 : tiles;
    const int wu = bh * 40 + ubase + c;
    const bool direct = (p < 4);                  // nc==1: no merge needed

    const int tid = threadIdx.x;
    const int wv = tid >> 6, lane = tid & 63;
    const int r31 = lane & 31, hi = lane >> 5, l7 = lane & 7;

    // 3-buffer ring: buf b at smem + b*8192 (K 4096 shorts, V 4096 shorts)
    __shared__ __align__(16) unsigned short smem[24576];    // 48 KB

    const unsigned short* kbase = kpg  + (size_t)bh * 131072;
    const unsigned short* vbase = vptg + (size_t)bh * 131072;

    const int qrow = p * 128 + wv * 32 + r31;
    const unsigned short* qp = qg + ((size_t)bh * 2048 + qrow) * 64 + 8 * hi;
    bf16x8 qf[4];
#pragma unroll
    for (int w = 0; w < 4; ++w)
        qf[w] = __builtin_bit_cast(bf16x8, *reinterpret_cast<const u16x8*>(qp + 16 * w));

    const u16x8 onesu = {0x3F80, 0x3F80, 0x3F80, 0x3F80, 0x3F80, 0x3F80, 0x3F80, 0x3F80};
    const bf16x8 onesf = __builtin_bit_cast(bf16x8, onesu);

    f32x16 oT0 = {0,0,0,0,0,0,0,0,0,0,0,0,0,0,0,0};
    f32x16 oT1 = {0,0,0,0,0,0,0,0,0,0,0,0,0,0,0,0};
    f32x16 lacc16 = {0,0,0,0,0,0,0,0,0,0,0,0,0,0,0,0};   // row-sum via ones-MFMA; elem 0 used
    const float CS = 0.18033688f;      // 0.125 * log2(e)

    // incremental staging source pointers: each stage() call = one tile, in order
    const int rr = lane >> 3;
    const int cg = (lane & 7) ^ rr;
    const unsigned short* ks0 = kbase + (size_t)(stBeg * 64 + wv * 8 + rr) * 64 + cg * 8;
    const unsigned short* ks1 = ks0 + 32 * 64;
    const unsigned short* vs0 = vbase + (size_t)(wv * 8 + rr) * 2048 + stBeg * 64 + cg * 8;
    const unsigned short* vs1 = vs0 + 32 * 2048;
    auto stage = [&](int buf) {                 // 4 loads per wave per call
        unsigned short* kb_ = smem + buf * 8192;
        GLDS16(ks0, kb_ + (wv * 8) * 64);
        GLDS16(ks1, kb_ + (wv * 8 + 32) * 64);
        GLDS16(vs0, kb_ + 4096 + (wv * 8) * 64);
        GLDS16(vs1, kb_ + 4096 + (wv * 8 + 32) * 64);
        ks0 += 4096; ks1 += 4096; vs0 += 64; vs1 += 64;
    };

    stage(0);
    if (stBeg + 1 < stEnd) stage(1);
    int cb = 0, sb = 2;                         // current / stage-target buffers
    for (int st = stBeg; st < stEnd; ++st) {
        // counted wait: tile st landed; tile st+1's 4 loads stay in flight
        if (st + 1 < stEnd) asm volatile("s_waitcnt vmcnt(4)" ::: "memory");
        else                asm volatile("s_waitcnt vmcnt(0)" ::: "memory");
        __builtin_amdgcn_sched_barrier(0);
        __builtin_amdgcn_s_barrier();           // raw barrier: no vmcnt(0) drain
        if (st + 2 < stEnd) stage(sb);          // overwrites tile st-1's buffer (safe post-barrier)

        const unsigned short* kcur = smem + cb * 8192;
        const unsigned short* vcur = kcur + 4096;
        const int rel0 = p * 128 + wv * 32 - st * 64;     // multiples of 32
        const int rel1 = rel0 - 32;
        const bool act0 = rel0 >= 0, act1 = rel1 >= 0;    // act1 => act0

        if (act0) {
            // ---- S^T = KP * Q^T : D[row=s][col=q]
            f32x16 sA0 = {0,0,0,0,0,0,0,0,0,0,0,0,0,0,0,0};
            f32x16 sA1 = {0,0,0,0,0,0,0,0,0,0,0,0,0,0,0,0};
            __builtin_amdgcn_s_setprio(1);
#pragma unroll
            for (int w = 0; w < 4; ++w) {
                bf16x8 k0 = __builtin_bit_cast(bf16x8, *reinterpret_cast<const u16x8*>(
                    &kcur[r31 * 64 + (((2 * w + hi) ^ l7) * 8)]));
                sA0 = MFMA32(k0, qf[w], sA0);
            }
            if (act1) {
#pragma unroll
                for (int w = 0; w < 4; ++w) {
                    bf16x8 k1 = __builtin_bit_cast(bf16x8, *reinterpret_cast<const u16x8*>(
                        &kcur[(32 + r31) * 64 + (((2 * w + hi) ^ l7) * 8)]));
                    sA1 = MFMA32(k1, qf[w], sA1);
                }
            }
            __builtin_amdgcn_s_setprio(0);
            // ---- causal mask (only rel==0 sblk is partial); exp2(-huge)=0
            if (rel0 == 0) {
#pragma unroll
                for (int reg = 0; reg < 16; ++reg) {
                    const int sp = (reg & 3) + 8 * (reg >> 2) + 4 * hi;
                    if (sp > r31) sA0[reg] = -3e38f;
                }
            }
            if (act1 && rel1 == 0) {
#pragma unroll
                for (int reg = 0; reg < 16; ++reg) {
                    const int sp = (reg & 3) + 8 * (reg >> 2) + 4 * hi;
                    if (sp > r31) sA1[reg] = -3e38f;
                }
            }

            // ---- sblk0: P = exp2(S*CS) -> pack -> PV + ones-MFMA row-sum
            {
                float pr[16];
#pragma unroll
                for (int reg = 0; reg < 16; ++reg) pr[reg] = __builtin_exp2f(sA0[reg] * CS);
                unsigned int wr_[8];
#pragma unroll
                for (int i = 0; i < 8; ++i)
                    asm("v_cvt_pk_bf16_f32 %0, %1, %2" : "=v"(wr_[i]) : "v"(pr[2 * i]), "v"(pr[2 * i + 1]));
                asm volatile("v_permlane32_swap_b32 %0, %1" : "+v"(wr_[0]), "+v"(wr_[2]));
                asm volatile("v_permlane32_swap_b32 %0, %1" : "+v"(wr_[1]), "+v"(wr_[3]));
                asm volatile("v_permlane32_swap_b32 %0, %1" : "+v"(wr_[4]), "+v"(wr_[6]));
                asm volatile("v_permlane32_swap_b32 %0, %1" : "+v"(wr_[5]), "+v"(wr_[7]));
                __builtin_amdgcn_s_setprio(1);
#pragma unroll
                for (int w = 0; w < 2; ++w) {     // s-windows 0,1
                    bf16x8 pa = __builtin_bit_cast(bf16x8, (uint4){wr_[4 * w], wr_[4 * w + 1], wr_[4 * w + 2], wr_[4 * w + 3]});
                    bf16x8 v0 = __builtin_bit_cast(bf16x8, *reinterpret_cast<const u16x8*>(
                        &vcur[r31 * 64 + (((2 * w + hi) ^ l7) * 8)]));
                    oT0 = MFMA32(v0, pa, oT0);
                    bf16x8 v1 = __builtin_bit_cast(bf16x8, *reinterpret_cast<const u16x8*>(
                        &vcur[(32 + r31) * 64 + (((2 * w + hi) ^ l7) * 8)]));
                    oT1 = MFMA32(v1, pa, oT1);
                    lacc16 = MFMA32(onesf, pa, lacc16);   // row-sum via matrix pipe
                }
                __builtin_amdgcn_s_setprio(0);
            }
            // ---- sblk1
            if (act1) {
                float pr[16];
#pragma unroll
                for (int reg = 0; reg < 16; ++reg) pr[reg] = __builtin_exp2f(sA1[reg] * CS);
                unsigned int wr_[8];
#pragma unroll
                for (int i = 0; i < 8; ++i)
                    asm("v_cvt_pk_bf16_f32 %0, %1, %2" : "=v"(wr_[i]) : "v"(pr[2 * i]), "v"(pr[2 * i + 1]));
                asm volatile("v_permlane32_swap_b32 %0, %1" : "+v"(wr_[0]), "+v"(wr_[2]));
                asm volatile("v_permlane32_swap_b32 %0, %1" : "+v"(wr_[1]), "+v"(wr_[3]));
                asm volatile("v_permlane32_swap_b32 %0, %1" : "+v"(wr_[4]), "+v"(wr_[6]));
                asm volatile("v_permlane32_swap_b32 %0, %1" : "+v"(wr_[5]), "+v"(wr_[7]));
                __builtin_amdgcn_s_setprio(1);
#pragma unroll
                for (int w = 2; w < 4; ++w) {     // s-windows 2,3
                    bf16x8 pa = __builtin_bit_cast(bf16x8, (uint4){wr_[4 * (w - 2)], wr_[4 * (w - 2) + 1], wr_[4 * (w - 2) + 2], wr_[4 * (w - 2) + 3]});
                    bf16x8 v0 = __builtin_bit_cast(bf16x8, *reinterpret_cast<const u16x8*>(
                        &vcur[r31 * 64 + (((2 * w + hi) ^ l7) * 8)]));
                    oT0 = MFMA32(v0, pa, oT0);
                    bf16x8 v1 = __builtin_bit_cast(bf16x8, *reinterpret_cast<const u16x8*>(
                        &vcur[(32 + r31) * 64 + (((2 * w + hi) ^ l7) * 8)]));
                    oT1 = MFMA32(v1, pa, oT1);
                    lacc16 = MFMA32(onesf, pa, lacc16);
                }
                __builtin_amdgcn_s_setprio(0);
            }
        }
        cb = (cb == 2) ? 0 : cb + 1;
        sb = (sb == 2) ? 0 : sb + 1;
    }

    // ---- epilogue: normalize (direct) -> LDS-transpose -> coalesced store
    __syncthreads();
    if (direct) {
        const float invL = 1.0f / lacc16[0];
#pragma unroll
        for (int reg = 0; reg < 16; ++reg) { oT0[reg] *= invL; oT1[reg] *= invL; }
    }
    unsigned int* tr = reinterpret_cast<unsigned int*>(smem) + wv * 1056;   // [32 q][33] u32
#pragma unroll
    for (int i = 0; i < 8; ++i) {
        unsigned int wda, wdb;
        asm("v_cvt_pk_bf16_f32 %0, %1, %2" : "=v"(wda) : "v"(oT0[2 * i]), "v"(oT0[2 * i + 1]));
        asm("v_cvt_pk_bf16_f32 %0, %1, %2" : "=v"(wdb) : "v"(oT1[2 * i]), "v"(oT1[2 * i + 1]));
        const int col = (i & 1) + 4 * (i >> 1) + 2 * hi;
        tr[r31 * 33 + col] = wda;
        tr[r31 * 33 + 16 + col] = wdb;
    }
    if (direct) {
        const int b = bh >> 4, h = bh & 15;
        const int t = p * 128 + wv * 32 + r31;
        const size_t gb2 = ((size_t)(b * 2048 + t)) * 1024 + h * 64 + 32 * hi;
#pragma unroll
        for (int cc = 0; cc < 4; ++cc) {
            uint4 v = *reinterpret_cast<uint4*>(&tr[r31 * 33 + 16 * hi + 4 * cc]);
            *reinterpret_cast<uint4*>(&og[gb2 + 8 * cc]) = v;
        }
    } else {
        const size_t gb = (size_t)wu * 8192 + (size_t)(wv * 32 + r31) * 64 + 32 * hi;
#pragma unroll
        for (int cc = 0; cc < 4; ++cc) {
            uint4 v = *reinterpret_cast<uint4*>(&tr[r31 * 33 + 16 * hi + 4 * cc]);
            *reinterpret_cast<uint4*>(&pO[gb + 8 * cc]) = v;
        }
        if (hi == 0)
            pML[(size_t)wu * 128 + wv * 32 + r31] = lacc16[0];
    }
}

// ---------------------------------------------------------------- split-K attention, phase B (merge)
// Fixed-offset softmax: plain sum. p<4 handled directly by attn_part -> skip.
__global__ __launch_bounds__(256) void attn_merge(
    const unsigned short* __restrict__ pO, const float* __restrict__ pML,
    unsigned short* __restrict__ og) {
    const int bx = blockIdx.x;             // [0,512)
    const int xcd = bx & 7, j = bx >> 3;   // [0,64)
    const int bhl = j & 3, p = j >> 2;     // p in [0,16)
    if (p < 4) return;                     // nc==1: written directly by attn_part
    const int bh = xcd * 4 + bhl;
    const int nc = (p >> 2) + 1;
    int ubase;
    if (p < 8)       ubase = 4 + 2 * (p - 4);
    else if (p < 12) ubase = 12 + 3 * (p - 8);
    else             ubase = 24 + 4 * (p - 12);
    const int wu0 = bh * 40 + ubase;

    const int tid = threadIdx.x;
    const int q = tid >> 1, dh = (tid & 1) * 32;   // thread = half-row (32 d)

    float L = 0.f;
#pragma unroll
    for (int c2 = 0; c2 < 4; ++c2)
        if (c2 < nc) L += pML[(size_t)(wu0 + c2) * 128 + q];
    const float invL = 1.0f / L;

    float acc[32];
#pragma unroll
    for (int i = 0; i < 32; ++i) acc[i] = 0.f;
#pragma unroll
    for (int c2 = 0; c2 < 4; ++c2) {
        if (c2 < nc) {
            const unsigned short* src = pO + (size_t)(wu0 + c2) * 8192 + q * 64 + dh;
#pragma unroll
            for (int v4 = 0; v4 < 4; ++v4) {
                u16x8 v = *reinterpret_cast<const u16x8*>(src + v4 * 8);
#pragma unroll
                for (int i = 0; i < 8; ++i)
                    acc[v4 * 8 + i] += bf2f(v[i]);
            }
        }
    }
    const int b = bh >> 4, h = bh & 15;
    const int t = p * 128 + q;
    unsigned short* dst = og + ((size_t)(b * 2048 + t)) * 1024 + h * 64 + dh;
#pragma unroll
    for (int v4 = 0; v4 < 8; ++v4) {
        ushort4 o;
        o.x = bfc(acc[v4 * 4] * invL); o.y = bfc(acc[v4 * 4 + 1] * invL);
        o.z = bfc(acc[v4 * 4 + 2] * invL); o.w = bfc(acc[v4 * 4 + 3] * invL);
        reinterpret_cast<ushort4*>(dst)[v4] = o;
    }
}

// ---------------------------------------------------------------- launch
extern "C" void kernel_launch(void* const* d_in, const int* in_sizes, int n_in,
                              void* d_out, int out_size, void* d_ws, size_t ws_size,
                              hipStream_t stream) {
    const float* x  = (const float*)d_in[0];
    const float* Wq = (const float*)d_in[1];
    const float* Wk = (const float*)d_in[2];
    const float* Wv = (const float*)d_in[3];
    const float* E  = (const float*)d_in[4];
    const float* F  = (const float*)d_in[5];
    const float* Wp = (const float*)d_in[6];
    const float* bp = (const float*)d_in[7];
    float* out = (float*)d_out;

    char* ws = (char*)d_ws;
    unsigned short* qw   = (unsigned short*)(ws);               // [32][2048][64] bf16 (8 MB)
    unsigned short* kpw  = (unsigned short*)(ws + 8388608);     // [32][2048][64] bf16 (8 MB)
    unsigned short* vptw = (unsigned short*)(ws + 16777216);    // [32][64][2048] bf16 (8 MB)
    unsigned short* ow   = (unsigned short*)(ws + 25165824);    // 4096x1024 bf16 (8 MB)
    unsigned short* wpb  = (unsigned short*)(ws + 33554432);    // 1024x1024 bf16 (2 MB)
    unsigned short* xb   = (unsigned short*)(ws + 35651584);    // 4096x1024 bf16 (8 MB)  [dead after gemm0]
    unsigned short* wcat = (unsigned short*)(ws + 44040192);    // 3072x1024 bf16 (6 MB)  [dead after gemm0]
    unsigned short* pO   = (unsigned short*)(ws + 35651584);    // 1280x8192 bf16 (20 MB) [overlays xb/wcat]
    float*          pML  = (float*)(ws + 56623104);             // 1280x128 f32 (0.64 MB)

    prep2<<<2048, 256, 0, stream>>>(x, Wq, Wp, Wk, Wv, E, F, xb, wcat, wpb);
    gemm_bt<0><<<dim3(32, 24), 256, 0, stream>>>(xb, wcat, 1024, qw, kpw, vptw, nullptr, nullptr);
    attn_part<<<1280, 256, 0, stream>>>(qw, kpw, vptw, pO, pML, ow);
    attn_merge<<<512, 256, 0, stream>>>(pO, pML, ow);
    gemm_bt<1><<<dim3(32, 8), 256, 0, stream>>>(ow, wpb, 1024, nullptr, nullptr, nullptr, out, bp);
}

// Round 17
// 122.832 us; speedup vs baseline: 1.0884x; 1.0884x over previous
//
#include <hip/hip_runtime.h>

typedef __attribute__((ext_vector_type(8))) __bf16 bf16x8;
typedef __attribute__((ext_vector_type(4))) float f32x4;
typedef __attribute__((ext_vector_type(16))) float f32x16;
typedef __attribute__((ext_vector_type(8))) unsigned short u16x8;

#define MFMA16(a, b, c) __builtin_amdgcn_mfma_f32_16x16x32_bf16((a), (b), (c), 0, 0, 0)
#define MFMA32(a, b, c) __builtin_amdgcn_mfma_f32_32x32x16_bf16((a), (b), (c), 0, 0, 0)

// async global->LDS, 16B per lane; dst must be wave-uniform base (lane*16B auto)
#define GLDS16(g, l) __builtin_amdgcn_global_load_lds( \
    (const __attribute__((address_space(1))) unsigned int*)(const void*)(g), \
    (__attribute__((address_space(3))) unsigned int*)(void*)(l), 16, 0, 0)

__device__ __forceinline__ unsigned short bfc(float f) {
    __bf16 h = (__bf16)f;
    return __builtin_bit_cast(unsigned short, h);
}
__device__ __forceinline__ float bf2f(unsigned short u) {
    return __builtin_bit_cast(float, (unsigned int)u << 16);
}

// ---------------------------------------------------------------- f32 -> bf16 converts (x, Wq, Wp)
// 1536 blocks x 256 thr x 4 consecutive float4/thread (ILP-4, 64B/lane).
__global__ __launch_bounds__(256) void convert_all(
    const float* __restrict__ x, const float* __restrict__ wq, const float* __restrict__ wp,
    unsigned short* __restrict__ xb, unsigned short* __restrict__ wcat, unsigned short* __restrict__ wpb) {
    int i0 = (blockIdx.x * 256 + threadIdx.x) * 4;    // float4 index, [0, 1572864)
    const float* s; unsigned short* d;
    if (i0 < 1048576)      { s = x;  d = xb; }
    else if (i0 < 1310720) { i0 -= 1048576; s = wq; d = wcat; }
    else                   { i0 -= 1310720; s = wp; d = wpb; }
#pragma unroll
    for (int k = 0; k < 4; ++k) {
        float4 v = reinterpret_cast<const float4*>(s)[i0 + k];
        ushort4 o;
        o.x = bfc(v.x); o.y = bfc(v.y); o.z = bfc(v.z); o.w = bfc(v.w);
        reinterpret_cast<ushort4*>(d)[i0 + k] = o;
    }
}

// ---------------------------------------------------------------- WkE / WvF fold
// 512 blocks (2/CU TLP), thread = 4 kk x 4 c, unroll 8 -> 8 outstanding W-row loads.
__global__ __launch_bounds__(256) void build_wkev(
    const float* __restrict__ Wk, const float* __restrict__ Wv,
    const float* __restrict__ E, const float* __restrict__ F,
    unsigned short* __restrict__ wcat) {
    __shared__ float Els[4096];          // E_h: [64 d][64 kk] f32 (16 KB)
    const int bx = blockIdx.x;           // 512 blocks: sel(2) x h(16) x cs(16)
    const int sel = bx >> 8, h = (bx >> 4) & 15, cs = bx & 15;
    const int tid = threadIdx.x;
    const int ko = tid >> 4, cq = tid & 15;
    const int c = cs * 64 + cq * 4;

    const float* W  = sel ? Wv : Wk;
    const float* Ef = (sel ? F : E) + (size_t)h * 4096;
#pragma unroll
    for (int i = tid; i < 1024; i += 256)
        reinterpret_cast<float4*>(Els)[i] = reinterpret_cast<const float4*>(Ef)[i];
    __syncthreads();

    float acc[4][4];
#pragma unroll
    for (int j = 0; j < 4; ++j)
#pragma unroll
        for (int t = 0; t < 4; ++t) acc[j][t] = 0.f;

#pragma unroll 8
    for (int d = 0; d < 64; ++d) {
        float4 wv4 = *reinterpret_cast<const float4*>(&W[(size_t)(h * 64 + d) * 1024 + c]);
        float4 e = *reinterpret_cast<const float4*>(&Els[d * 64 + ko * 4]);
        float ev[4] = {e.x, e.y, e.z, e.w};
#pragma unroll
        for (int j = 0; j < 4; ++j) {
            acc[j][0] = fmaf(ev[j], wv4.x, acc[j][0]);
            acc[j][1] = fmaf(ev[j], wv4.y, acc[j][1]);
            acc[j][2] = fmaf(ev[j], wv4.z, acc[j][2]);
            acc[j][3] = fmaf(ev[j], wv4.w, acc[j][3]);
        }
    }
#pragma unroll
    for (int j = 0; j < 4; ++j) {
        const int row = 1024 + (sel << 10) + h * 64 + ko * 4 + j;
        ushort4 o;
        o.x = bfc(acc[j][0]); o.y = bfc(acc[j][1]); o.z = bfc(acc[j][2]); o.w = bfc(acc[j][3]);
        *reinterpret_cast<ushort4*>(&wcat[(size_t)row * 1024 + c]) = o;
    }
}

// ---------------------------------------------------------------- bf16 GEMM, B^T layout
// 2-phase double-buffered staging: 1 barrier/iter, loads fly under compute.
template <int MODE>
__global__ __launch_bounds__(256) void gemm_bt(
    const unsigned short* __restrict__ A, const unsigned short* __restrict__ Bt, int K,
    unsigned short* __restrict__ qo, unsigned short* __restrict__ kpo, unsigned short* __restrict__ vpto,
    float* __restrict__ out, const float* __restrict__ bp) {
    __shared__ __align__(16) unsigned short As[2][4096];
    __shared__ __align__(16) unsigned short Bs[2][4096];
    const int tid = threadIdx.x;
    const int lane = tid & 63, wv = tid >> 6;
    const int g = lane >> 4, ln = lane & 15;
    const int wm = wv >> 1, wn = wv & 1;
    const int m0 = blockIdx.x * 128, n0 = blockIdx.y * 128;
    const int wvb = wv * 512;

    f32x4 acc[4][4];
#pragma unroll
    for (int i = 0; i < 4; ++i)
#pragma unroll
        for (int j = 0; j < 4; ++j) acc[i][j] = (f32x4){0.f, 0.f, 0.f, 0.f};

    const int c0 = tid, c1 = 256 + tid;
    const int row0 = c0 >> 2, k80 = c0 & 3;
    const int row1 = c1 >> 2, k81 = c1 & 3;

    auto stage = [&](int buf, int kt) {
        const int kb = kt * 32;
        GLDS16(A  + (size_t)(m0 + row0) * K + kb + k80 * 8, As[buf] + wvb);
        GLDS16(A  + (size_t)(m0 + row1) * K + kb + k81 * 8, As[buf] + 2048 + wvb);
        GLDS16(Bt + (size_t)(n0 + row0) * K + kb + k80 * 8, Bs[buf] + wvb);
        GLDS16(Bt + (size_t)(n0 + row1) * K + kb + k81 * 8, Bs[buf] + 2048 + wvb);
    };

    const int nk = K >> 5;
    stage(0, 0);
    for (int kt = 0; kt < nk; ++kt) {
        const int cur = kt & 1;
        __syncthreads();                          // buf[cur] landed; buf[cur^1] reads done
        if (kt + 1 < nk) stage(cur ^ 1, kt + 1);  // next-tile loads fly under this compute
        bf16x8 af[4], bfr[4];
#pragma unroll
        for (int i = 0; i < 4; ++i)
            af[i] = __builtin_bit_cast(bf16x8, *reinterpret_cast<const u16x8*>(As[cur] + (wm * 64 + i * 16 + ln) * 32 + g * 8));
#pragma unroll
        for (int j = 0; j < 4; ++j)
            bfr[j] = __builtin_bit_cast(bf16x8, *reinterpret_cast<const u16x8*>(Bs[cur] + (wn * 64 + j * 16 + ln) * 32 + g * 8));
#pragma unroll
        for (int i = 0; i < 4; ++i)
#pragma unroll
            for (int j = 0; j < 4; ++j)
                acc[i][j] = MFMA16(af[i], bfr[j], acc[i][j]);
    }

#pragma unroll
    for (int i = 0; i < 4; ++i) {
        const int mbase = m0 + wm * 64 + i * 16 + 4 * g;
        const int b = mbase >> 11, t0 = mbase & 2047;
#pragma unroll
        for (int j = 0; j < 4; ++j) {
            const int ncol = n0 + wn * 64 + j * 16 + ln;
            if (MODE == 0) {
                const int sec = ncol >> 10, nn = ncol & 1023;
                const int h = nn >> 6, e = nn & 63;
                const int bh = b * 16 + h;
                if (sec == 2) {
                    ushort4 o;
                    o.x = bfc(acc[i][j][0]); o.y = bfc(acc[i][j][1]);
                    o.z = bfc(acc[i][j][2]); o.w = bfc(acc[i][j][3]);
                    *reinterpret_cast<ushort4*>(&vpto[(size_t)(bh * 64 + e) * 2048 + t0]) = o;
                } else {
#pragma unroll
                    for (int r = 0; r < 4; ++r) {
                        unsigned short val = bfc(acc[i][j][r]);
                        if (sec == 0) qo[(size_t)(bh * 2048 + t0 + r) * 64 + e] = val;
                        else          kpo[(size_t)(bh * 2048 + t0 + r) * 64 + e] = val;
                    }
                }
            } else {
#pragma unroll
                for (int r = 0; r < 4; ++r)
                    out[(size_t)(mbase + r) * 1024 + ncol] = acc[i][j][r] + bp[ncol];
            }
        }
    }
}

// ---------------------------------------------------------------- split-K flash attention, phase A
// Fixed-offset softmax: P = exp2(S*CS), l via ones-MFMA. 3-buffer KV ring +
// counted vmcnt. nc==1 WUs (p<4) normalize in-kernel and write og directly;
// multi-chunk WUs go through separate merge dispatch (R13: fused merge w/
// threadfence+atomic across XCDs cost 7x).
__attribute__((amdgpu_waves_per_eu(3, 4)))
__global__ __launch_bounds__(256) void attn_part(
    const unsigned short* __restrict__ qg, const unsigned short* __restrict__ kpg,
    const unsigned short* __restrict__ vptg,
    unsigned short* __restrict__ pO, float* __restrict__ pML,
    unsigned short* __restrict__ og) {
    const int bx = blockIdx.x;                    // [0,1280)
    const int xcd = bx & 7;
    const int j = bx >> 3;                        // [0,160)
    const int bhl = j & 3;
    const int u = 39 - (j >> 2);                  // long chunks first
    const int bh = xcd * 4 + bhl;                 // 4 heads per XCD
    int p, c;
    if (u < 4)       { p = u;                    c = 0; }
    else if (u < 12) { p = 4 + ((u - 4) >> 1);   c = (u - 4) & 1; }
    else if (u < 24) { p = 8 + (u - 12) / 3;     c = (u - 12) % 3; }
    else             { p = 12 + ((u - 24) >> 2); c = (u - 24) & 3; }
    int ubase;
    if (p < 4)       ubase = p;
    else if (p < 8)  ubase = 4 + 2 * (p - 4);
    else if (p < 12) ubase = 12 + 3 * (p - 8);
    else             ubase = 24 + 4 * (p - 12);
    const int tiles = (p == 15) ? 32 : (2 * p + 2);
    const int stBeg = c * 8;
    const int stEnd = (stBeg + 8 < tiles) ? stBeg + 8 : tiles;
    const int wu = bh * 40 + ubase + c;
    const bool direct = (p < 4);                  // nc==1: no merge needed

    const int tid = threadIdx.x;
    const int wv = tid >> 6, lane = tid & 63;
    const int r31 = lane & 31, hi = lane >> 5, l7 = lane & 7;

    // 3-buffer ring: buf b at smem + b*8192 (K 4096 shorts, V 4096 shorts)
    __shared__ __align__(16) unsigned short smem[24576];    // 48 KB

    const unsigned short* kbase = kpg  + (size_t)bh * 131072;
    const unsigned short* vbase = vptg + (size_t)bh * 131072;

    const int qrow = p * 128 + wv * 32 + r31;
    const unsigned short* qp = qg + ((size_t)bh * 2048 + qrow) * 64 + 8 * hi;
    bf16x8 qf[4];
#pragma unroll
    for (int w = 0; w < 4; ++w)
        qf[w] = __builtin_bit_cast(bf16x8, *reinterpret_cast<const u16x8*>(qp + 16 * w));

    const u16x8 onesu = {0x3F80, 0x3F80, 0x3F80, 0x3F80, 0x3F80, 0x3F80, 0x3F80, 0x3F80};
    const bf16x8 onesf = __builtin_bit_cast(bf16x8, onesu);

    f32x16 oT0 = {0,0,0,0,0,0,0,0,0,0,0,0,0,0,0,0};
    f32x16 oT1 = {0,0,0,0,0,0,0,0,0,0,0,0,0,0,0,0};
    f32x16 lacc16 = {0,0,0,0,0,0,0,0,0,0,0,0,0,0,0,0};   // row-sum via ones-MFMA; elem 0 used
    const float CS = 0.18033688f;      // 0.125 * log2(e)

    // incremental staging source pointers: each stage() call = one tile, in order
    const int rr = lane >> 3;
    const int cg = (lane & 7) ^ rr;
    const unsigned short* ks0 = kbase + (size_t)(stBeg * 64 + wv * 8 + rr) * 64 + cg * 8;
    const unsigned short* ks1 = ks0 + 32 * 64;
    const unsigned short* vs0 = vbase + (size_t)(wv * 8 + rr) * 2048 + stBeg * 64 + cg * 8;
    const unsigned short* vs1 = vs0 + 32 * 2048;
    auto stage = [&](int buf) {                 // 4 loads per wave per call
        unsigned short* kb_ = smem + buf * 8192;
        GLDS16(ks0, kb_ + (wv * 8) * 64);
        GLDS16(ks1, kb_ + (wv * 8 + 32) * 64);
        GLDS16(vs0, kb_ + 4096 + (wv * 8) * 64);
        GLDS16(vs1, kb_ + 4096 + (wv * 8 + 32) * 64);
        ks0 += 4096; ks1 += 4096; vs0 += 64; vs1 += 64;
    };

    stage(0);
    if (stBeg + 1 < stEnd) stage(1);
    int cb = 0, sb = 2;                         // current / stage-target buffers
    for (int st = stBeg; st < stEnd; ++st) {
        // counted wait: tile st landed; tile st+1's 4 loads stay in flight
        if (st + 1 < stEnd) asm volatile("s_waitcnt vmcnt(4)" ::: "memory");
        else                asm volatile("s_waitcnt vmcnt(0)" ::: "memory");
        __builtin_amdgcn_sched_barrier(0);
        __builtin_amdgcn_s_barrier();           // raw barrier: no vmcnt(0) drain
        if (st + 2 < stEnd) stage(sb);          // overwrites tile st-1's buffer (safe post-barrier)

        const unsigned short* kcur = smem + cb * 8192;
        const unsigned short* vcur = kcur + 4096;
        const int rel0 = p * 128 + wv * 32 - st * 64;     // multiples of 32
        const int rel1 = rel0 - 32;
        const bool act0 = rel0 >= 0, act1 = rel1 >= 0;    // act1 => act0

        if (act0) {
            // ---- S^T = KP * Q^T : D[row=s][col=q]
            f32x16 sA0 = {0,0,0,0,0,0,0,0,0,0,0,0,0,0,0,0};
            f32x16 sA1 = {0,0,0,0,0,0,0,0,0,0,0,0,0,0,0,0};
            __builtin_amdgcn_s_setprio(1);
#pragma unroll
            for (int w = 0; w < 4; ++w) {
                bf16x8 k0 = __builtin_bit_cast(bf16x8, *reinterpret_cast<const u16x8*>(
                    &kcur[r31 * 64 + (((2 * w + hi) ^ l7) * 8)]));
                sA0 = MFMA32(k0, qf[w], sA0);
            }
            if (act1) {
#pragma unroll
                for (int w = 0; w < 4; ++w) {
                    bf16x8 k1 = __builtin_bit_cast(bf16x8, *reinterpret_cast<const u16x8*>(
                        &kcur[(32 + r31) * 64 + (((2 * w + hi) ^ l7) * 8)]));
                    sA1 = MFMA32(k1, qf[w], sA1);
                }
            }
            __builtin_amdgcn_s_setprio(0);
            // ---- causal mask (only rel==0 sblk is partial); exp2(-huge)=0
            if (rel0 == 0) {
#pragma unroll
                for (int reg = 0; reg < 16; ++reg) {
                    const int sp = (reg & 3) + 8 * (reg >> 2) + 4 * hi;
                    if (sp > r31) sA0[reg] = -3e38f;
                }
            }
            if (act1 && rel1 == 0) {
#pragma unroll
                for (int reg = 0; reg < 16; ++reg) {
                    const int sp = (reg & 3) + 8 * (reg >> 2) + 4 * hi;
                    if (sp > r31) sA1[reg] = -3e38f;
                }
            }

            // ---- sblk0: P = exp2(S*CS) -> pack -> PV + ones-MFMA row-sum
            {
                float pr[16];
#pragma unroll
                for (int reg = 0; reg < 16; ++reg) pr[reg] = __builtin_exp2f(sA0[reg] * CS);
                unsigned int wr_[8];
#pragma unroll
                for (int i = 0; i < 8; ++i)
                    asm("v_cvt_pk_bf16_f32 %0, %1, %2" : "=v"(wr_[i]) : "v"(pr[2 * i]), "v"(pr[2 * i + 1]));
                asm volatile("v_permlane32_swap_b32 %0, %1" : "+v"(wr_[0]), "+v"(wr_[2]));
                asm volatile("v_permlane32_swap_b32 %0, %1" : "+v"(wr_[1]), "+v"(wr_[3]));
                asm volatile("v_permlane32_swap_b32 %0, %1" : "+v"(wr_[4]), "+v"(wr_[6]));
                asm volatile("v_permlane32_swap_b32 %0, %1" : "+v"(wr_[5]), "+v"(wr_[7]));
                __builtin_amdgcn_s_setprio(1);
#pragma unroll
                for (int w = 0; w < 2; ++w) {     // s-windows 0,1
                    bf16x8 pa = __builtin_bit_cast(bf16x8, (uint4){wr_[4 * w], wr_[4 * w + 1], wr_[4 * w + 2], wr_[4 * w + 3]});
                    bf16x8 v0 = __builtin_bit_cast(bf16x8, *reinterpret_cast<const u16x8*>(
                        &vcur[r31 * 64 + (((2 * w + hi) ^ l7) * 8)]));
                    oT0 = MFMA32(v0, pa, oT0);
                    bf16x8 v1 = __builtin_bit_cast(bf16x8, *reinterpret_cast<const u16x8*>(
                        &vcur[(32 + r31) * 64 + (((2 * w + hi) ^ l7) * 8)]));
                    oT1 = MFMA32(v1, pa, oT1);
                    lacc16 = MFMA32(onesf, pa, lacc16);   // row-sum via matrix pipe
                }
                __builtin_amdgcn_s_setprio(0);
            }
            // ---- sblk1
            if (act1) {
                float pr[16];
#pragma unroll
                for (int reg = 0; reg < 16; ++reg) pr[reg] = __builtin_exp2f(sA1[reg] * CS);
                unsigned int wr_[8];
#pragma unroll
                for (int i = 0; i < 8; ++i)
                    asm("v_cvt_pk_bf16_f32 %0, %1, %2" : "=v"(wr_[i]) : "v"(pr[2 * i]), "v"(pr[2 * i + 1]));
                asm volatile("v_permlane32_swap_b32 %0, %1" : "+v"(wr_[0]), "+v"(wr_[2]));
                asm volatile("v_permlane32_swap_b32 %0, %1" : "+v"(wr_[1]), "+v"(wr_[3]));
                asm volatile("v_permlane32_swap_b32 %0, %1" : "+v"(wr_[4]), "+v"(wr_[6]));
                asm volatile("v_permlane32_swap_b32 %0, %1" : "+v"(wr_[5]), "+v"(wr_[7]));
                __builtin_amdgcn_s_setprio(1);
#pragma unroll
                for (int w = 2; w < 4; ++w) {     // s-windows 2,3
                    bf16x8 pa = __builtin_bit_cast(bf16x8, (uint4){wr_[4 * (w - 2)], wr_[4 * (w - 2) + 1], wr_[4 * (w - 2) + 2], wr_[4 * (w - 2) + 3]});
                    bf16x8 v0 = __builtin_bit_cast(bf16x8, *reinterpret_cast<const u16x8*>(
                        &vcur[r31 * 64 + (((2 * w + hi) ^ l7) * 8)]));
                    oT0 = MFMA32(v0, pa, oT0);
                    bf16x8 v1 = __builtin_bit_cast(bf16x8, *reinterpret_cast<const u16x8*>(
                        &vcur[(32 + r31) * 64 + (((2 * w + hi) ^ l7) * 8)]));
                    oT1 = MFMA32(v1, pa, oT1);
                    lacc16 = MFMA32(onesf, pa, lacc16);
                }
                __builtin_amdgcn_s_setprio(0);
            }
        }
        cb = (cb == 2) ? 0 : cb + 1;
        sb = (sb == 2) ? 0 : sb + 1;
    }

    // ---- epilogue: normalize (direct) -> LDS-transpose -> coalesced store
    __syncthreads();
    if (direct) {
        const float invL = 1.0f / lacc16[0];
#pragma unroll
        for (int reg = 0; reg < 16; ++reg) { oT0[reg] *= invL; oT1[reg] *= invL; }
    }
    unsigned int* tr = reinterpret_cast<unsigned int*>(smem) + wv * 1056;   // [32 q][33] u32
#pragma unroll
    for (int i = 0; i < 8; ++i) {
        unsigned int wda, wdb;
        asm("v_cvt_pk_bf16_f32 %0, %1, %2" : "=v"(wda) : "v"(oT0[2 * i]), "v"(oT0[2 * i + 1]));
        asm("v_cvt_pk_bf16_f32 %0, %1, %2" : "=v"(wdb) : "v"(oT1[2 * i]), "v"(oT1[2 * i + 1]));
        const int col = (i & 1) + 4 * (i >> 1) + 2 * hi;
        tr[r31 * 33 + col] = wda;
        tr[r31 * 33 + 16 + col] = wdb;
    }
    if (direct) {
        const int b = bh >> 4, h = bh & 15;
        const int t = p * 128 + wv * 32 + r31;
        const size_t gb2 = ((size_t)(b * 2048 + t)) * 1024 + h * 64 + 32 * hi;
#pragma unroll
        for (int cc = 0; cc < 4; ++cc) {
            uint4 v = *reinterpret_cast<uint4*>(&tr[r31 * 33 + 16 * hi + 4 * cc]);
            *reinterpret_cast<uint4*>(&og[gb2 + 8 * cc]) = v;
        }
    } else {
        const size_t gb = (size_t)wu * 8192 + (size_t)(wv * 32 + r31) * 64 + 32 * hi;
#pragma unroll
        for (int cc = 0; cc < 4; ++cc) {
            uint4 v = *reinterpret_cast<uint4*>(&tr[r31 * 33 + 16 * hi + 4 * cc]);
            *reinterpret_cast<uint4*>(&pO[gb + 8 * cc]) = v;
        }
        if (hi == 0)
            pML[(size_t)wu * 128 + wv * 32 + r31] = lacc16[0];
    }
}

// ---------------------------------------------------------------- split-K attention, phase B (merge)
// Fixed-offset softmax: plain sum. p<4 handled directly by attn_part -> skip.
__global__ __launch_bounds__(256) void attn_merge(
    const unsigned short* __restrict__ pO, const float* __restrict__ pML,
    unsigned short* __restrict__ og) {
    const int bx = blockIdx.x;             // [0,512)
    const int xcd = bx & 7, j = bx >> 3;   // [0,64)
    const int bhl = j & 3, p = j >> 2;     // p in [0,16)
    if (p < 4) return;                     // nc==1: written directly by attn_part
    const int bh = xcd * 4 + bhl;
    const int nc = (p >> 2) + 1;
    int ubase;
    if (p < 8)       ubase = 4 + 2 * (p - 4);
    else if (p < 12) ubase = 12 + 3 * (p - 8);
    else             ubase = 24 + 4 * (p - 12);
    const int wu0 = bh * 40 + ubase;

    const int tid = threadIdx.x;
    const int q = tid >> 1, dh = (tid & 1) * 32;   // thread = half-row (32 d)

    float L = 0.f;
#pragma unroll
    for (int c2 = 0; c2 < 4; ++c2)
        if (c2 < nc) L += pML[(size_t)(wu0 + c2) * 128 + q];
    const float invL = 1.0f / L;

    float acc[32];
#pragma unroll
    for (int i = 0; i < 32; ++i) acc[i] = 0.f;
#pragma unroll
    for (int c2 = 0; c2 < 4; ++c2) {
        if (c2 < nc) {
            const unsigned short* src = pO + (size_t)(wu0 + c2) * 8192 + q * 64 + dh;
#pragma unroll
            for (int v4 = 0; v4 < 4; ++v4) {
                u16x8 v = *reinterpret_cast<const u16x8*>(src + v4 * 8);
#pragma unroll
                for (int i = 0; i < 8; ++i)
                    acc[v4 * 8 + i] += bf2f(v[i]);
            }
        }
    }
    const int b = bh >> 4, h = bh & 15;
    const int t = p * 128 + q;
    unsigned short* dst = og + ((size_t)(b * 2048 + t)) * 1024 + h * 64 + dh;
#pragma unroll
    for (int v4 = 0; v4 < 8; ++v4) {
        ushort4 o;
        o.x = bfc(acc[v4 * 4] * invL); o.y = bfc(acc[v4 * 4 + 1] * invL);
        o.z = bfc(acc[v4 * 4 + 2] * invL); o.w = bfc(acc[v4 * 4 + 3] * invL);
        reinterpret_cast<ushort4*>(dst)[v4] = o;
    }
}

// ---------------------------------------------------------------- launch
extern "C" void kernel_launch(void* const* d_in, const int* in_sizes, int n_in,
                              void* d_out, int out_size, void* d_ws, size_t ws_size,
                              hipStream_t stream) {
    const float* x  = (const float*)d_in[0];
    const float* Wq = (const float*)d_in[1];
    const float* Wk = (const float*)d_in[2];
    const float* Wv = (const float*)d_in[3];
    const float* E  = (const float*)d_in[4];
    const float* F  = (const float*)d_in[5];
    const float* Wp = (const float*)d_in[6];
    const float* bp = (const float*)d_in[7];
    float* out = (float*)d_out;

    char* ws = (char*)d_ws;
    unsigned short* qw   = (unsigned short*)(ws);               // [32][2048][64] bf16 (8 MB)
    unsigned short* kpw  = (unsigned short*)(ws + 8388608);     // [32][2048][64] bf16 (8 MB)
    unsigned short* vptw = (unsigned short*)(ws + 16777216);    // [32][64][2048] bf16 (8 MB)
    unsigned short* ow   = (unsigned short*)(ws + 25165824);    // 4096x1024 bf16 (8 MB)
    unsigned short* wpb  = (unsigned short*)(ws + 33554432);    // 1024x1024 bf16 (2 MB)
    unsigned short* xb   = (unsigned short*)(ws + 35651584);    // 4096x1024 bf16 (8 MB)  [dead after gemm0]
    unsigned short* wcat = (unsigned short*)(ws + 44040192);    // 3072x1024 bf16 (6 MB)  [dead after gemm0]
    unsigned short* pO   = (unsigned short*)(ws + 35651584);    // 1280x8192 bf16 (20 MB) [overlays xb/wcat]
    float*          pML  = (float*)(ws + 56623104);             // 1280x128 f32 (0.64 MB)

    convert_all<<<1536, 256, 0, stream>>>(x, Wq, Wp, xb, wcat, wpb);
    build_wkev<<<512, 256, 0, stream>>>(Wk, Wv, E, F, wcat);
    gemm_bt<0><<<dim3(32, 24), 256, 0, stream>>>(xb, wcat, 1024, qw, kpw, vptw, nullptr, nullptr);
    attn_part<<<1280, 256, 0, stream>>>(qw, kpw, vptw, pO, pML, ow);
    attn_merge<<<512, 256, 0, stream>>>(pO, pML, ow);
    gemm_bt<1><<<dim3(32, 8), 256, 0, stream>>>(ow, wpb, 1024, nullptr, nullptr, nullptr, out, bp);
}